// Round 6
// baseline (285.529 us; speedup 1.0000x reference)
//
#include <hip/hip_runtime.h>

#define TPB 256
#define HID 128
#define IN_C 4
#define SLOT_C 32          // per-node slot capacity; Poisson(16): P(deg>32)~1e-4,
                           // ~10 overflow nodes @ n=1e5 -> ovf list handles them.
#define NB 512             // dst-range buckets (~196 nodes each @ n=1e5)
#define EPT 8              // edges per thread in k_part
#define ECAP 4096          // per-bucket edge capacity (mean 3125, sigma 56 -> 17 sigma)
#define OVF_CAP 131072     // overflow pairs capacity (statistically needs ~100)

typedef __attribute__((ext_vector_type(8))) short bf16x8;   // 8 bf16 = 4 VGPRs
typedef __attribute__((ext_vector_type(4))) float f32x4;

union FragU { uint4 u; bf16x8 b; };

// bf16 helpers: pack with RNE, unpack with shift (values finite, no NaN)
__device__ __forceinline__ unsigned f2bf(float f) {
    unsigned u = __float_as_uint(f);
    return (u + 0x7fffu + ((u >> 16) & 1u)) >> 16;
}
__device__ __forceinline__ float bf_lo(unsigned u) { return __uint_as_float(u << 16); }
__device__ __forceinline__ float bf_hi(unsigned u) { return __uint_as_float(u & 0xffff0000u); }

// ---------------------------------------------------------------------------
// K0: fused prep — role by blockIdx: [0,nbA) zero cursor/out; [nbA,nbA+64)
// w2frag swizzle; last block: per-graph 1/cnt + ovf_cnt=0 + pcur[NB]=0.
__global__ void k_prep(int* cursor, float* out, int n, int outsz,
                       const float* __restrict__ W2, unsigned short* w2f,
                       const int* __restrict__ batch, float* rcnt, int bg,
                       int* ovf_cnt, int* pcur) {
    int nbA = (n + TPB - 1) / TPB;
    int b = blockIdx.x;
    if (b < nbA) {
        int i = b * TPB + threadIdx.x;
        if (i < n) cursor[i] = 0;
        if (i < outsz) out[i] = 0.0f;
    } else if (b < nbA + 64) {
        int i = (b - nbA) * TPB + threadIdx.x;   // 0..16383
        if (i < HID * HID) {
            int j = i & 7, frag = i >> 3;
            int lane = frag & 63, blk = frag >> 6;       // blk = kk*8 + nt
            int kk = blk >> 3, nt = blk & 7;
            int quad = lane >> 4, nloc = lane & 15;
            int k = kk * 32 + quad * 8 + j;
            int c = nt * 16 + nloc;
            w2f[i] = (unsigned short)f2bf(W2[k * HID + c]);
        }
    } else {
        int g = threadIdx.x;
        if (g == 0) *ovf_cnt = 0;
        for (int z = g; z < NB; z += TPB) pcur[z] = 0;
        if (g < bg) {
            int lo0 = 0, hi0 = n;
            while (lo0 < hi0) { int m = (lo0 + hi0) >> 1; if (batch[m] < g) lo0 = m + 1; else hi0 = m; }
            int lo1 = lo0, hi1 = n;
            while (lo1 < hi1) { int m = (lo1 + hi1) >> 1; if (batch[m] < g + 1) lo1 = m + 1; else hi1 = m; }
            int c = lo1 - lo0;
            rcnt[g] = 1.0f / (float)(c > 1 ? c : 1);
        }
    }
}

// K1a: bucket edges into NB=512 dst-range buckets, one pass. Rank via
// 2-copy x 512-counter LDS histogram (half-wave picks its copy).
__global__ __launch_bounds__(256) void k_part(
        const int* __restrict__ src, const int* __restrict__ dst,
        int2* elist, int* pcur, int e, int n) {
    __shared__ int lcnt[2][NB];
    __shared__ int lbase[NB];
    int t = threadIdx.x;
    int c = (t >> 5) & 1;                    // half-wave copy id
    for (int z = t; z < NB; z += 256) { lcnt[0][z] = 0; lcnt[1][z] = 0; }
    __syncthreads();

    int base_i = blockIdx.x * (256 * EPT);
    int s[EPT], d[EPT], pr[EPT];
#pragma unroll
    for (int k = 0; k < EPT; k++) {
        int i = base_i + k * 256 + t;
        if (i < e) {
            s[k] = src[i];
            d[k] = dst[i];
            int p = (int)(((long long)d[k] * NB) / n);
            int r = atomicAdd(&lcnt[c][p], 1);     // LDS, ~conflict-free
            pr[k] = p | (r << 9);                   // p<512, r<2048
        } else {
            pr[k] = -1;
        }
    }
    __syncthreads();

    for (int z = t; z < NB; z += 256) {
        int tot = lcnt[0][z] + lcnt[1][z];
        lbase[z] = tot ? atomicAdd(&pcur[z], tot) : 0;
    }
    __syncthreads();

#pragma unroll
    for (int k = 0; k < EPT; k++) {
        if (pr[k] >= 0) {
            int p = pr[k] & (NB - 1);
            int r = pr[k] >> 9;
            int idx = lbase[p] + (c ? lcnt[0][p] : 0) + r;
            if (idx < ECAP)                         // 17-sigma slack; never taken
                elist[(size_t)p * ECAP + idx] = make_int2(s[k], d[k]);
        }
    }
}

// K1b: build slots, ONE BLOCK PER BUCKET. Per-node cursors in LDS; zero
// global atomics on the hot path; degrees + dinv written once per node at
// the end (k_dinv folded in here).
__global__ __launch_bounds__(256) void k_build(
        const int2* __restrict__ elist, const int* __restrict__ pcur,
        int* cursor, float* dinv, int* slots, int* ovf, int* ovf_cnt, int n) {
    __shared__ int lcur[512];                // covers n <= NB*512
    int p = blockIdx.x;
    int t = threadIdx.x;
    int nlo = (int)(((long long)p * n + NB - 1) / NB);       // ceil(p*n/NB)
    int nhi = (int)(((long long)(p + 1) * n + NB - 1) / NB);
    int nn = nhi - nlo;
    for (int z = t; z < nn; z += 256) lcur[z] = 0;
    __syncthreads();

    int ne = pcur[p];
    if (ne > ECAP) ne = ECAP;
    for (int j = t; j < ne; j += 256) {
        int2 ed = elist[(size_t)p * ECAP + j];
        int pos = atomicAdd(&lcur[ed.y - nlo], 1);
        if (pos < SLOT_C) {
            slots[ed.y * SLOT_C + pos] = ed.x;
        } else {                              // rare (P~1e-4 per node)
            int o = atomicAdd(ovf_cnt, 1);
            if (o < OVF_CAP) {
                ovf[2 * o] = ed.x;
                ovf[2 * o + 1] = ed.y;
            }
        }
    }
    __syncthreads();
    for (int z = t; z < nn; z += 256) {
        int dg = lcur[z];
        cursor[nlo + z] = dg;
        dinv[nlo + z] = rsqrtf((float)dg + 1.0f);
    }
}

// K6: FUSED layer-1 gather + W1 MLP -> packed bf16 f1p (row-major: 64 words
// = 128 channels per node).
__global__ __launch_bounds__(256) void k_g1f1(
        const int* __restrict__ cursor, const int* __restrict__ slots,
        const int* __restrict__ ovf, const int* __restrict__ ovf_cnt,
        const float* __restrict__ dinv, const float* __restrict__ x,
        const float* __restrict__ W1, const float* __restrict__ b1,
        unsigned* f1p, int n) {
    __shared__ float xs[256 * 5];
    int t = threadIdx.x;
    int v0 = blockIdx.x * 256;

    // ---- phase A: gather (one thread per node) ----
    int v = v0 + t;
    if (v < n) {
        float dv = dinv[v];
        const float4* x4 = (const float4*)x;
        float4 xv = x4[v];
        float sl = dv * dv;
        float4 A = make_float4(sl * xv.x, sl * xv.y, sl * xv.z, sl * xv.w);
        float4 B = make_float4(0.f, 0.f, 0.f, 0.f);
        float4 C = make_float4(0.f, 0.f, 0.f, 0.f);
        float4 D = make_float4(0.f, 0.f, 0.f, 0.f);
        int deg = cursor[v];
        int m = deg < SLOT_C ? deg : SLOT_C;
        const int* sb = slots + v * SLOT_C;
        int e = 0;
        for (; e + 4 <= m; e += 4) {
            int s0 = sb[e], s1 = sb[e + 1], s2 = sb[e + 2], s3 = sb[e + 3];
            float n0 = dinv[s0] * dv, n1 = dinv[s1] * dv;
            float n2 = dinv[s2] * dv, n3 = dinv[s3] * dv;
            float4 r0 = x4[s0], r1 = x4[s1], r2 = x4[s2], r3 = x4[s3];
            A.x = fmaf(n0, r0.x, A.x); A.y = fmaf(n0, r0.y, A.y);
            A.z = fmaf(n0, r0.z, A.z); A.w = fmaf(n0, r0.w, A.w);
            B.x = fmaf(n1, r1.x, B.x); B.y = fmaf(n1, r1.y, B.y);
            B.z = fmaf(n1, r1.z, B.z); B.w = fmaf(n1, r1.w, B.w);
            C.x = fmaf(n2, r2.x, C.x); C.y = fmaf(n2, r2.y, C.y);
            C.z = fmaf(n2, r2.z, C.z); C.w = fmaf(n2, r2.w, C.w);
            D.x = fmaf(n3, r3.x, D.x); D.y = fmaf(n3, r3.y, D.y);
            D.z = fmaf(n3, r3.z, D.z); D.w = fmaf(n3, r3.w, D.w);
        }
        for (; e < m; e++) {
            int s = sb[e];
            float nm = dinv[s] * dv;
            float4 r = x4[s];
            A.x = fmaf(nm, r.x, A.x); A.y = fmaf(nm, r.y, A.y);
            A.z = fmaf(nm, r.z, A.z); A.w = fmaf(nm, r.w, A.w);
        }
        if (deg > SLOT_C) {              // only truncated nodes scan the list
            int oc = *ovf_cnt;
            for (int k = 0; k < oc; k++) {
                if (ovf[2 * k + 1] == v) {
                    int s = ovf[2 * k];
                    float nm = dinv[s] * dv;
                    float4 r = x4[s];
                    A.x = fmaf(nm, r.x, A.x); A.y = fmaf(nm, r.y, A.y);
                    A.z = fmaf(nm, r.z, A.z); A.w = fmaf(nm, r.w, A.w);
                }
            }
        }
        xs[t * 5 + 0] = (A.x + B.x) + (C.x + D.x);
        xs[t * 5 + 1] = (A.y + B.y) + (C.y + D.y);
        xs[t * 5 + 2] = (A.z + B.z) + (C.z + D.z);
        xs[t * 5 + 3] = (A.w + B.w) + (C.w + D.w);
    }
    __syncthreads();

    // ---- phase B: W1 MLP + relu + bf16 pack ----
    int cp = t & 63;                     // constant per thread
    int c0 = cp * 2, c1 = c0 + 1;
    float w00 = W1[c0],           w01 = W1[c1];
    float w10 = W1[HID + c0],     w11 = W1[HID + c1];
    float w20 = W1[2 * HID + c0], w21 = W1[2 * HID + c1];
    float w30 = W1[3 * HID + c0], w31 = W1[3 * HID + c1];
    float bb0 = b1[c0],           bb1 = b1[c1];
    int g = t >> 6;                      // node sub-group 0..3 (wave-uniform)
    for (int iter = 0; iter < 64; iter++) {
        int node = iter * 4 + g;
        int vv = v0 + node;
        if (vv >= n) break;              // wave-uniform
        float x0 = xs[node * 5 + 0], x1 = xs[node * 5 + 1];
        float x2 = xs[node * 5 + 2], x3 = xs[node * 5 + 3];
        float s0 = fmaf(x0, w00, fmaf(x1, w10, fmaf(x2, w20, fmaf(x3, w30, bb0))));
        float s1 = fmaf(x0, w01, fmaf(x1, w11, fmaf(x2, w21, fmaf(x3, w31, bb1))));
        s0 = s0 > 0.0f ? s0 : 0.0f;
        s1 = s1 > 0.0f ? s1 : 0.0f;
        f1p[(size_t)vv * 64 + cp] = f2bf(s0) | (f2bf(s1) << 16);
    }
}

// K8+K9 FUSED: layer-2 gather (round-2 split-wave uint2 body, unchanged) ->
// LDS row staging -> MFMA GEMM + bias/ReLU/mean-pool. Each wave gathers its
// own 16 nodes (rows w*16..w*16+15) then consumes exactly those rows as its
// MFMA A-fragments. Kills the 25 MB acc2b write + 25.6 MB re-read + 1 launch.
// arow padded [64][68]: ds_read_b128 in MFMA phase = 2-way bank alias (free).
__global__ __launch_bounds__(256) void k_g2mm(
        const int* __restrict__ cursor, const int* __restrict__ slots,
        const int* __restrict__ ovf, const int* __restrict__ ovf_cnt,
        const float* __restrict__ dinv, const unsigned* __restrict__ f1p,
        const unsigned short* __restrict__ w2f, const float* __restrict__ b2,
        const int* __restrict__ batch, const float* __restrict__ rcnt,
        float* out, int n) {
    __shared__ unsigned arow[64][68];
    __shared__ int bch[64];
    int t = threadIdx.x;
    int w = t >> 6, ln = t & 63;
    int v0 = blockIdx.x * 64;
    if (t < 64) {
        int v = v0 + t;
        bch[t] = (v < n) ? batch[v] : -1;
    }
    if (v0 + 64 > n) {                       // tail block: zero all A rows
        for (int z = t; z < 64 * 68; z += 256) ((unsigned*)arow)[z] = 0;
    }
    __syncthreads();

    // ---- phase 1: gather 16 nodes per wave (round-2 body per node) ----
    int h = ln >> 5;                     // half = edge parity
    int q = ln & 31;                     // channel quad: ch 4q..4q+3
    const uint2* F = (const uint2*)f1p;  // row = 32 uint2
    for (int nd = 0; nd < 16; nd++) {
        int row = w * 16 + nd;
        int v = v0 + row;
        if (v >= n) break;               // wave-uniform
        float dv = dinv[v];

        uint2 us = F[(size_t)v * 32 + q];
        float sl = (h == 0) ? dv * dv : 0.0f;
        float A[4] = { sl * bf_lo(us.x), sl * bf_hi(us.x),
                       sl * bf_lo(us.y), sl * bf_hi(us.y) };
        float B[4] = {0.f, 0.f, 0.f, 0.f};
        float C[4] = {0.f, 0.f, 0.f, 0.f};
        float D[4] = {0.f, 0.f, 0.f, 0.f};

        int deg = cursor[v];
        int m = deg < SLOT_C ? deg : SLOT_C;
        const int* sb = slots + v * SLOT_C;
        int e = 0;
        for (; e + 8 <= m; e += 8) {
            int sA = sb[e + h];
            int sB = sb[e + 2 + h];
            int sC = sb[e + 4 + h];
            int sD = sb[e + 6 + h];
            float nA = dinv[sA] * dv, nB = dinv[sB] * dv;
            float nC = dinv[sC] * dv, nD = dinv[sD] * dv;
            uint2 uA = F[(size_t)sA * 32 + q];
            uint2 uB = F[(size_t)sB * 32 + q];
            uint2 uC = F[(size_t)sC * 32 + q];
            uint2 uD = F[(size_t)sD * 32 + q];
            A[0] = fmaf(nA, bf_lo(uA.x), A[0]); A[1] = fmaf(nA, bf_hi(uA.x), A[1]);
            A[2] = fmaf(nA, bf_lo(uA.y), A[2]); A[3] = fmaf(nA, bf_hi(uA.y), A[3]);
            B[0] = fmaf(nB, bf_lo(uB.x), B[0]); B[1] = fmaf(nB, bf_hi(uB.x), B[1]);
            B[2] = fmaf(nB, bf_lo(uB.y), B[2]); B[3] = fmaf(nB, bf_hi(uB.y), B[3]);
            C[0] = fmaf(nC, bf_lo(uC.x), C[0]); C[1] = fmaf(nC, bf_hi(uC.x), C[1]);
            C[2] = fmaf(nC, bf_lo(uC.y), C[2]); C[3] = fmaf(nC, bf_hi(uC.y), C[3]);
            D[0] = fmaf(nD, bf_lo(uD.x), D[0]); D[1] = fmaf(nD, bf_hi(uD.x), D[1]);
            D[2] = fmaf(nD, bf_lo(uD.y), D[2]); D[3] = fmaf(nD, bf_hi(uD.y), D[3]);
        }
        for (; e + 2 <= m; e += 2) {
            int s = sb[e + h];
            float nm = dinv[s] * dv;
            uint2 u = F[(size_t)s * 32 + q];
            A[0] = fmaf(nm, bf_lo(u.x), A[0]); A[1] = fmaf(nm, bf_hi(u.x), A[1]);
            A[2] = fmaf(nm, bf_lo(u.y), A[2]); A[3] = fmaf(nm, bf_hi(u.y), A[3]);
        }
        if (e < m) {                     // odd tail: half 0 only
            int s = sb[e];
            float nm = (h == 0) ? dinv[s] * dv : 0.0f;
            uint2 u = F[(size_t)s * 32 + q];
            A[0] = fmaf(nm, bf_lo(u.x), A[0]); A[1] = fmaf(nm, bf_hi(u.x), A[1]);
            A[2] = fmaf(nm, bf_lo(u.y), A[2]); A[3] = fmaf(nm, bf_hi(u.y), A[3]);
        }
        if (deg > SLOT_C) {              // only truncated nodes scan the list
            int oc = *ovf_cnt;
            for (int k = 0; k < oc; k++) {
                if (ovf[2 * k + 1] == v && h == 0) {
                    int s = ovf[2 * k];
                    float nm = dinv[s] * dv;
                    uint2 u = F[(size_t)s * 32 + q];
                    A[0] = fmaf(nm, bf_lo(u.x), A[0]); A[1] = fmaf(nm, bf_hi(u.x), A[1]);
                    A[2] = fmaf(nm, bf_lo(u.y), A[2]); A[3] = fmaf(nm, bf_hi(u.y), A[3]);
                }
            }
        }

        float o0 = (A[0] + B[0]) + (C[0] + D[0]);
        float o1 = (A[1] + B[1]) + (C[1] + D[1]);
        float o2 = (A[2] + B[2]) + (C[2] + D[2]);
        float o3 = (A[3] + B[3]) + (C[3] + D[3]);
        o0 += __shfl_xor(o0, 32, 64);
        o1 += __shfl_xor(o1, 32, 64);
        o2 += __shfl_xor(o2, 32, 64);
        o3 += __shfl_xor(o3, 32, 64);
        if (h == 0) {
            arow[row][2 * q]     = f2bf(o0) | (f2bf(o1) << 16);
            arow[row][2 * q + 1] = f2bf(o2) | (f2bf(o3) << 16);
        }
    }
    __syncthreads();

    // ---- phase 2: MFMA + bias/ReLU/mean-pool (round-5 body, A from LDS) ----
    int lane = ln;
    int quad = lane >> 4, nloc = lane & 15;
    const uint4* B4 = (const uint4*)w2f;        // frag blk = 64 uint4

    f32x4 acc[8];
#pragma unroll
    for (int nt = 0; nt < 8; nt++) acc[nt] = (f32x4){0.f, 0.f, 0.f, 0.f};

#pragma unroll
    for (int kk = 0; kk < 4; kk++) {
        FragU af;
        af.u = *(const uint4*)&arow[w * 16 + nloc][(kk * 4 + quad) * 4];
#pragma unroll
        for (int nt = 0; nt < 8; nt++) {
            FragU bf;
            bf.u = B4[(kk * 8 + nt) * 64 + lane];
            acc[nt] = __builtin_amdgcn_mfma_f32_16x16x32_bf16(af.b, bf.b, acc[nt], 0, 0, 0);
        }
    }

    int b0 = bch[w * 16], b15 = bch[w * 16 + 15];
    if (b0 == b15 && b0 >= 0) {
        float rc = rcnt[b0];
#pragma unroll
        for (int nt = 0; nt < 8; nt++) {
            float bias = b2[nt * 16 + nloc];
            float s = 0.f;
#pragma unroll
            for (int reg = 0; reg < 4; reg++) {
                float f = acc[nt][reg] + bias;
                s += f > 0.f ? f : 0.f;
            }
            s += __shfl_xor(s, 16, 64);
            s += __shfl_xor(s, 32, 64);
            if (lane < 16) atomicAdd(&out[b0 * HID + nt * 16 + lane], s * rc);
        }
    } else {
#pragma unroll
        for (int nt = 0; nt < 8; nt++) {
            float bias = b2[nt * 16 + nloc];
            int cur = -1; float run = 0.f;
#pragma unroll
            for (int reg = 0; reg < 4; reg++) {
                int b = bch[w * 16 + quad * 4 + reg];
                if (b < 0) continue;
                float f = acc[nt][reg] + bias;
                f = f > 0.f ? f : 0.f;
                if (b != cur) {
                    if (cur >= 0) atomicAdd(&out[cur * HID + nt * 16 + nloc], run * rcnt[cur]);
                    run = 0.f; cur = b;
                }
                run += f;
            }
            if (cur >= 0) atomicAdd(&out[cur * HID + nt * 16 + nloc], run * rcnt[cur]);
        }
    }
}

extern "C" void kernel_launch(void* const* d_in, const int* in_sizes, int n_in,
                              void* d_out, int out_size, void* d_ws, size_t ws_size,
                              hipStream_t stream) {
    const float* x   = (const float*)d_in[0];
    const int* ei    = (const int*)d_in[1];   // [2, E] flat: src then dst
    const int* batch = (const int*)d_in[2];
    const float* W1  = (const float*)d_in[3];
    const float* b1  = (const float*)d_in[4];
    const float* W2  = (const float*)d_in[5];
    const float* b2  = (const float*)d_in[6];
    float* out = (float*)d_out;

    int n  = in_sizes[0] / IN_C;
    int e  = in_sizes[1] / 2;
    int bg = out_size / HID;
    const int* src = ei;
    const int* dst = ei + e;

    size_t off_b = 0;
    char* base = (char*)d_ws;
    auto carve = [&](size_t bytes) -> void* {
        void* p = base + off_b;
        off_b += (bytes + 255) & ~(size_t)255;
        return p;
    };
    int*            cursor  = (int*)carve((size_t)n * 4);
    int*            slots   = (int*)carve((size_t)n * SLOT_C * 4);
    int*            ovf     = (int*)carve((size_t)OVF_CAP * 2 * 4);
    int*            ovf_cnt = (int*)carve(256);
    int*            pcur    = (int*)carve((size_t)NB * 4);
    int2*           elist   = (int2*)carve((size_t)NB * ECAP * 8);
    float*          dinv    = (float*)carve((size_t)n * 4);
    unsigned*       f1p     = (unsigned*)carve((size_t)n * 64 * 4);    // bf16-packed
    unsigned short* w2f     = (unsigned short*)carve((size_t)HID * HID * 2);
    float*          rcnt    = (float*)carve((size_t)bg * 4);
    (void)ws_size;

    int gN = (n + TPB - 1) / TPB;
    int gP = (e + 256 * EPT - 1) / (256 * EPT);

    k_prep<<<gN + 64 + 1, TPB, 0, stream>>>(cursor, out, n, out_size, W2, w2f,
                                            batch, rcnt, bg, ovf_cnt, pcur);
    k_part<<<gP, TPB, 0, stream>>>(src, dst, elist, pcur, e, n);
    k_build<<<NB, TPB, 0, stream>>>(elist, pcur, cursor, dinv, slots, ovf, ovf_cnt, n);
    k_g1f1<<<gN, TPB, 0, stream>>>(cursor, slots, ovf, ovf_cnt, dinv, x, W1, b1, f1p, n);
    k_g2mm<<<(n + 63) / 64, 256, 0, stream>>>(cursor, slots, ovf, ovf_cnt, dinv, f1p,
                                              w2f, b2, batch, rcnt, out, n);
}

// Round 7
// 242.368 us; speedup vs baseline: 1.1781x; 1.1781x over previous
//
#include <hip/hip_runtime.h>

#define TPB 256
#define HID 128
#define IN_C 4
#define SLOT_C 32          // per-node slot capacity; Poisson(16): P(deg>32)~1e-4,
                           // ~10 overflow nodes @ n=1e5 -> ovf list handles them.
#define NB 512             // dst-range buckets (~196 nodes each @ n=1e5)
#define EPT 8              // edges per thread in k_part
#define ECAP 4096          // per-bucket edge capacity (mean 3125, sigma 56 -> 17 sigma)
#define OVF_CAP 131072     // overflow pairs capacity (statistically needs ~100)

typedef __attribute__((ext_vector_type(8))) short bf16x8;   // 8 bf16 = 4 VGPRs
typedef __attribute__((ext_vector_type(4))) float f32x4;

union FragU { uint4 u; bf16x8 b; };

// bf16 helpers: pack with RNE, unpack with shift (values finite, no NaN)
__device__ __forceinline__ unsigned f2bf(float f) {
    unsigned u = __float_as_uint(f);
    return (u + 0x7fffu + ((u >> 16) & 1u)) >> 16;
}
__device__ __forceinline__ float bf_lo(unsigned u) { return __uint_as_float(u << 16); }
__device__ __forceinline__ float bf_hi(unsigned u) { return __uint_as_float(u & 0xffff0000u); }

// ---------------------------------------------------------------------------
// K0: fused prep — role by blockIdx: [0,nbA) zero out (cursor zeroing DROPPED:
// k_build fully rewrites cursor); [nbA,nbA+64) w2frag swizzle; last block:
// per-graph 1/cnt + ovf_cnt=0 + pcur[NB]=0.
__global__ void k_prep(float* out, int n, int outsz,
                       const float* __restrict__ W2, unsigned short* w2f,
                       const int* __restrict__ batch, float* rcnt, int bg,
                       int* ovf_cnt, int* pcur) {
    int nbA = (n + TPB - 1) / TPB;
    int b = blockIdx.x;
    if (b < nbA) {
        int i = b * TPB + threadIdx.x;
        if (i < outsz) out[i] = 0.0f;
    } else if (b < nbA + 64) {
        int i = (b - nbA) * TPB + threadIdx.x;   // 0..16383
        if (i < HID * HID) {
            int j = i & 7, frag = i >> 3;
            int lane = frag & 63, blk = frag >> 6;       // blk = kk*8 + nt
            int kk = blk >> 3, nt = blk & 7;
            int quad = lane >> 4, nloc = lane & 15;
            int k = kk * 32 + quad * 8 + j;
            int c = nt * 16 + nloc;
            w2f[i] = (unsigned short)f2bf(W2[k * HID + c]);
        }
    } else {
        int g = threadIdx.x;
        if (g == 0) *ovf_cnt = 0;
        for (int z = g; z < NB; z += TPB) pcur[z] = 0;
        if (g < bg) {
            int lo0 = 0, hi0 = n;
            while (lo0 < hi0) { int m = (lo0 + hi0) >> 1; if (batch[m] < g) lo0 = m + 1; else hi0 = m; }
            int lo1 = lo0, hi1 = n;
            while (lo1 < hi1) { int m = (lo1 + hi1) >> 1; if (batch[m] < g + 1) lo1 = m + 1; else hi1 = m; }
            int c = lo1 - lo0;
            rcnt[g] = 1.0f / (float)(c > 1 ? c : 1);
        }
    }
}

// K1a: bucket edges into NB=512 dst-range buckets, one pass. Rank via
// 2-copy x 512-counter LDS histogram (half-wave picks its copy).
// elist entry is PACKED 4B: s | ((d - nlo(p)) << 17)  (s<2^17, bucket-local
// d < 512) -> halves the elist round-trip vs int2.
__global__ __launch_bounds__(256) void k_part(
        const int* __restrict__ src, const int* __restrict__ dst,
        unsigned* elist, int* pcur, int e, int n) {
    __shared__ int lcnt[2][NB];
    __shared__ int lbase[NB];
    int t = threadIdx.x;
    int c = (t >> 5) & 1;                    // half-wave copy id
    for (int z = t; z < NB; z += 256) { lcnt[0][z] = 0; lcnt[1][z] = 0; }
    __syncthreads();

    int base_i = blockIdx.x * (256 * EPT);
    unsigned u[EPT]; int pr[EPT];
#pragma unroll
    for (int k = 0; k < EPT; k++) {
        int i = base_i + k * 256 + t;
        if (i < e) {
            int s = src[i];
            int d = dst[i];
            int p = (int)(((long long)d * NB) / n);
            int nlo = (int)(((long long)p * n + NB - 1) / NB);   // ceil(p*n/NB)
            int r = atomicAdd(&lcnt[c][p], 1);     // LDS, ~conflict-free
            pr[k] = p | (r << 9);                   // p<512, r<2048
            u[k] = (unsigned)s | ((unsigned)(d - nlo) << 17);
        } else {
            pr[k] = -1;
        }
    }
    __syncthreads();

    for (int z = t; z < NB; z += 256) {
        int tot = lcnt[0][z] + lcnt[1][z];
        lbase[z] = tot ? atomicAdd(&pcur[z], tot) : 0;
    }
    __syncthreads();

#pragma unroll
    for (int k = 0; k < EPT; k++) {
        if (pr[k] >= 0) {
            int p = pr[k] & (NB - 1);
            int r = pr[k] >> 9;
            int idx = lbase[p] + (c ? lcnt[0][p] : 0) + r;
            if (idx < ECAP)                         // 17-sigma slack; never taken
                elist[(size_t)p * ECAP + idx] = u[k];
        }
    }
}

// K1b: build slots, ONE BLOCK PER BUCKET. Per-node cursors in LDS; zero
// global atomics on the hot path; degrees + dinv written once per node at
// the end (k_dinv folded in here). Reads packed 4B elist entries.
__global__ __launch_bounds__(256) void k_build(
        const unsigned* __restrict__ elist, const int* __restrict__ pcur,
        int* cursor, float* dinv, int* slots, int* ovf, int* ovf_cnt, int n) {
    __shared__ int lcur[512];                // covers n <= NB*512
    int p = blockIdx.x;
    int t = threadIdx.x;
    int nlo = (int)(((long long)p * n + NB - 1) / NB);       // ceil(p*n/NB)
    int nhi = (int)(((long long)(p + 1) * n + NB - 1) / NB);
    int nn = nhi - nlo;
    for (int z = t; z < nn; z += 256) lcur[z] = 0;
    __syncthreads();

    int ne = pcur[p];
    if (ne > ECAP) ne = ECAP;
    for (int j = t; j < ne; j += 256) {
        unsigned u = elist[(size_t)p * ECAP + j];
        int s = (int)(u & 0x1FFFFu);
        int dloc = (int)(u >> 17);
        int pos = atomicAdd(&lcur[dloc], 1);
        if (pos < SLOT_C) {
            slots[(nlo + dloc) * SLOT_C + pos] = s;
        } else {                              // rare (P~1e-4 per node)
            int o = atomicAdd(ovf_cnt, 1);
            if (o < OVF_CAP) {
                ovf[2 * o] = s;
                ovf[2 * o + 1] = nlo + dloc;
            }
        }
    }
    __syncthreads();
    for (int z = t; z < nn; z += 256) {
        int dg = lcur[z];
        cursor[nlo + z] = dg;
        dinv[nlo + z] = rsqrtf((float)dg + 1.0f);
    }
}

// K6: FUSED layer-1 gather + W1 MLP -> packed bf16 f1p (row-major: 64 words
// = 128 channels per node).
__global__ __launch_bounds__(256) void k_g1f1(
        const int* __restrict__ cursor, const int* __restrict__ slots,
        const int* __restrict__ ovf, const int* __restrict__ ovf_cnt,
        const float* __restrict__ dinv, const float* __restrict__ x,
        const float* __restrict__ W1, const float* __restrict__ b1,
        unsigned* f1p, int n) {
    __shared__ float xs[256 * 5];
    int t = threadIdx.x;
    int v0 = blockIdx.x * 256;

    // ---- phase A: gather (one thread per node) ----
    int v = v0 + t;
    if (v < n) {
        float dv = dinv[v];
        const float4* x4 = (const float4*)x;
        float4 xv = x4[v];
        float sl = dv * dv;
        float4 A = make_float4(sl * xv.x, sl * xv.y, sl * xv.z, sl * xv.w);
        float4 B = make_float4(0.f, 0.f, 0.f, 0.f);
        float4 C = make_float4(0.f, 0.f, 0.f, 0.f);
        float4 D = make_float4(0.f, 0.f, 0.f, 0.f);
        int deg = cursor[v];
        int m = deg < SLOT_C ? deg : SLOT_C;
        const int* sb = slots + v * SLOT_C;
        int e = 0;
        for (; e + 4 <= m; e += 4) {
            int s0 = sb[e], s1 = sb[e + 1], s2 = sb[e + 2], s3 = sb[e + 3];
            float n0 = dinv[s0] * dv, n1 = dinv[s1] * dv;
            float n2 = dinv[s2] * dv, n3 = dinv[s3] * dv;
            float4 r0 = x4[s0], r1 = x4[s1], r2 = x4[s2], r3 = x4[s3];
            A.x = fmaf(n0, r0.x, A.x); A.y = fmaf(n0, r0.y, A.y);
            A.z = fmaf(n0, r0.z, A.z); A.w = fmaf(n0, r0.w, A.w);
            B.x = fmaf(n1, r1.x, B.x); B.y = fmaf(n1, r1.y, B.y);
            B.z = fmaf(n1, r1.z, B.z); B.w = fmaf(n1, r1.w, B.w);
            C.x = fmaf(n2, r2.x, C.x); C.y = fmaf(n2, r2.y, C.y);
            C.z = fmaf(n2, r2.z, C.z); C.w = fmaf(n2, r2.w, C.w);
            D.x = fmaf(n3, r3.x, D.x); D.y = fmaf(n3, r3.y, D.y);
            D.z = fmaf(n3, r3.z, D.z); D.w = fmaf(n3, r3.w, D.w);
        }
        for (; e < m; e++) {
            int s = sb[e];
            float nm = dinv[s] * dv;
            float4 r = x4[s];
            A.x = fmaf(nm, r.x, A.x); A.y = fmaf(nm, r.y, A.y);
            A.z = fmaf(nm, r.z, A.z); A.w = fmaf(nm, r.w, A.w);
        }
        if (deg > SLOT_C) {              // only truncated nodes scan the list
            int oc = *ovf_cnt;
            for (int k = 0; k < oc; k++) {
                if (ovf[2 * k + 1] == v) {
                    int s = ovf[2 * k];
                    float nm = dinv[s] * dv;
                    float4 r = x4[s];
                    A.x = fmaf(nm, r.x, A.x); A.y = fmaf(nm, r.y, A.y);
                    A.z = fmaf(nm, r.z, A.z); A.w = fmaf(nm, r.w, A.w);
                }
            }
        }
        xs[t * 5 + 0] = (A.x + B.x) + (C.x + D.x);
        xs[t * 5 + 1] = (A.y + B.y) + (C.y + D.y);
        xs[t * 5 + 2] = (A.z + B.z) + (C.z + D.z);
        xs[t * 5 + 3] = (A.w + B.w) + (C.w + D.w);
    }
    __syncthreads();

    // ---- phase B: W1 MLP + relu + bf16 pack ----
    int cp = t & 63;                     // constant per thread
    int c0 = cp * 2, c1 = c0 + 1;
    float w00 = W1[c0],           w01 = W1[c1];
    float w10 = W1[HID + c0],     w11 = W1[HID + c1];
    float w20 = W1[2 * HID + c0], w21 = W1[2 * HID + c1];
    float w30 = W1[3 * HID + c0], w31 = W1[3 * HID + c1];
    float bb0 = b1[c0],           bb1 = b1[c1];
    int g = t >> 6;                      // node sub-group 0..3 (wave-uniform)
    for (int iter = 0; iter < 64; iter++) {
        int node = iter * 4 + g;
        int vv = v0 + node;
        if (vv >= n) break;              // wave-uniform
        float x0 = xs[node * 5 + 0], x1 = xs[node * 5 + 1];
        float x2 = xs[node * 5 + 2], x3 = xs[node * 5 + 3];
        float s0 = fmaf(x0, w00, fmaf(x1, w10, fmaf(x2, w20, fmaf(x3, w30, bb0))));
        float s1 = fmaf(x0, w01, fmaf(x1, w11, fmaf(x2, w21, fmaf(x3, w31, bb1))));
        s0 = s0 > 0.0f ? s0 : 0.0f;
        s1 = s1 > 0.0f ? s1 : 0.0f;
        f1p[(size_t)vv * 64 + cp] = f2bf(s0) | (f2bf(s1) << 16);
    }
}

// K8: layer-2 gather (round-2 structure: split-wave uint2, best measured;
// 68 us floor, pinned by random-granule memory service rate).
__global__ __launch_bounds__(128) void k_gather2(
        const int* __restrict__ cursor, const int* __restrict__ slots,
        const int* __restrict__ ovf, const int* __restrict__ ovf_cnt,
        const float* __restrict__ dinv, const unsigned* __restrict__ f1p,
        unsigned* acc2b, int n) {
    int wv = threadIdx.x >> 6;           // wave id 0..1
    int ln = threadIdx.x & 63;
    int h  = ln >> 5;                    // half = edge parity
    int q  = ln & 31;                    // channel quad: ch 4q..4q+3
    int v = blockIdx.x * 2 + wv;
    if (v >= n) return;
    float dv = dinv[v];
    const uint2* F = (const uint2*)f1p;  // row = 32 uint2

    uint2 us = F[(size_t)v * 32 + q];
    float sl = (h == 0) ? dv * dv : 0.0f;
    float A[4] = { sl * bf_lo(us.x), sl * bf_hi(us.x),
                   sl * bf_lo(us.y), sl * bf_hi(us.y) };
    float B[4] = {0.f, 0.f, 0.f, 0.f};
    float C[4] = {0.f, 0.f, 0.f, 0.f};
    float D[4] = {0.f, 0.f, 0.f, 0.f};

    int deg = cursor[v];
    int m = deg < SLOT_C ? deg : SLOT_C;
    const int* sb = slots + v * SLOT_C;
    int e = 0;
    for (; e + 8 <= m; e += 8) {
        int sA = sb[e + h];
        int sB = sb[e + 2 + h];
        int sC = sb[e + 4 + h];
        int sD = sb[e + 6 + h];
        float nA = dinv[sA] * dv, nB = dinv[sB] * dv;
        float nC = dinv[sC] * dv, nD = dinv[sD] * dv;
        uint2 uA = F[(size_t)sA * 32 + q];
        uint2 uB = F[(size_t)sB * 32 + q];
        uint2 uC = F[(size_t)sC * 32 + q];
        uint2 uD = F[(size_t)sD * 32 + q];
        A[0] = fmaf(nA, bf_lo(uA.x), A[0]); A[1] = fmaf(nA, bf_hi(uA.x), A[1]);
        A[2] = fmaf(nA, bf_lo(uA.y), A[2]); A[3] = fmaf(nA, bf_hi(uA.y), A[3]);
        B[0] = fmaf(nB, bf_lo(uB.x), B[0]); B[1] = fmaf(nB, bf_hi(uB.x), B[1]);
        B[2] = fmaf(nB, bf_lo(uB.y), B[2]); B[3] = fmaf(nB, bf_hi(uB.y), B[3]);
        C[0] = fmaf(nC, bf_lo(uC.x), C[0]); C[1] = fmaf(nC, bf_hi(uC.x), C[1]);
        C[2] = fmaf(nC, bf_lo(uC.y), C[2]); C[3] = fmaf(nC, bf_hi(uC.y), C[3]);
        D[0] = fmaf(nD, bf_lo(uD.x), D[0]); D[1] = fmaf(nD, bf_hi(uD.x), D[1]);
        D[2] = fmaf(nD, bf_lo(uD.y), D[2]); D[3] = fmaf(nD, bf_hi(uD.y), D[3]);
    }
    for (; e + 2 <= m; e += 2) {
        int s = sb[e + h];
        float nm = dinv[s] * dv;
        uint2 u = F[(size_t)s * 32 + q];
        A[0] = fmaf(nm, bf_lo(u.x), A[0]); A[1] = fmaf(nm, bf_hi(u.x), A[1]);
        A[2] = fmaf(nm, bf_lo(u.y), A[2]); A[3] = fmaf(nm, bf_hi(u.y), A[3]);
    }
    if (e < m) {                         // odd tail: half 0 only
        int s = sb[e];
        float nm = (h == 0) ? dinv[s] * dv : 0.0f;
        uint2 u = F[(size_t)s * 32 + q];
        A[0] = fmaf(nm, bf_lo(u.x), A[0]); A[1] = fmaf(nm, bf_hi(u.x), A[1]);
        A[2] = fmaf(nm, bf_lo(u.y), A[2]); A[3] = fmaf(nm, bf_hi(u.y), A[3]);
    }
    if (deg > SLOT_C) {                  // only truncated nodes scan the list
        int oc = *ovf_cnt;
        for (int k = 0; k < oc; k++) {
            if (ovf[2 * k + 1] == v && h == 0) {
                int s = ovf[2 * k];
                float nm = dinv[s] * dv;
                uint2 u = F[(size_t)s * 32 + q];
                A[0] = fmaf(nm, bf_lo(u.x), A[0]); A[1] = fmaf(nm, bf_hi(u.x), A[1]);
                A[2] = fmaf(nm, bf_lo(u.y), A[2]); A[3] = fmaf(nm, bf_hi(u.y), A[3]);
            }
        }
    }

    float o0 = (A[0] + B[0]) + (C[0] + D[0]);
    float o1 = (A[1] + B[1]) + (C[1] + D[1]);
    float o2 = (A[2] + B[2]) + (C[2] + D[2]);
    float o3 = (A[3] + B[3]) + (C[3] + D[3]);
    o0 += __shfl_xor(o0, 32, 64);
    o1 += __shfl_xor(o1, 32, 64);
    o2 += __shfl_xor(o2, 32, 64);
    o3 += __shfl_xor(o3, 32, 64);
    if (h == 0) {
        uint2 w;
        w.x = f2bf(o0) | (f2bf(o1) << 16);
        w.y = f2bf(o2) | (f2bf(o3) << 16);
        ((uint2*)acc2b)[(size_t)v * 32 + q] = w;
    }
}

// K9: MFMA GEMM + fused bias/ReLU/segment-MEAN-pool (k_div folded: each
// node's contribution is pre-scaled by 1/cnt[graph] before the atomic).
__global__ __launch_bounds__(256) void k_mm2_pool(
        const unsigned* __restrict__ acc2b, const unsigned short* __restrict__ w2f,
        const float* __restrict__ b2, const int* __restrict__ batch,
        const float* __restrict__ rcnt, float* out, int n) {
    __shared__ int bch[64];
    int t = threadIdx.x;
    int w = t >> 6, lane = t & 63;
    int quad = lane >> 4, nloc = lane & 15;
    int v0 = blockIdx.x * 64;
    if (t < 64) {
        int v = v0 + t;
        bch[t] = (v < n) ? batch[v] : -1;
    }
    __syncthreads();

    int va = v0 + w * 16 + nloc;
    if (va >= n) va = n - 1;

    const uint4* A4 = (const uint4*)acc2b;      // row = 16 uint4
    const uint4* B4 = (const uint4*)w2f;        // frag blk = 64 uint4

    f32x4 acc[8];
#pragma unroll
    for (int nt = 0; nt < 8; nt++) acc[nt] = (f32x4){0.f, 0.f, 0.f, 0.f};

#pragma unroll
    for (int kk = 0; kk < 4; kk++) {
        FragU af;
        af.u = A4[(size_t)va * 16 + kk * 4 + quad];
#pragma unroll
        for (int nt = 0; nt < 8; nt++) {
            FragU bf;
            bf.u = B4[(kk * 8 + nt) * 64 + lane];
            acc[nt] = __builtin_amdgcn_mfma_f32_16x16x32_bf16(af.b, bf.b, acc[nt], 0, 0, 0);
        }
    }

    int b0 = bch[w * 16], b15 = bch[w * 16 + 15];
    if (b0 == b15 && b0 >= 0) {
        float rc = rcnt[b0];
#pragma unroll
        for (int nt = 0; nt < 8; nt++) {
            float bias = b2[nt * 16 + nloc];
            float s = 0.f;
#pragma unroll
            for (int reg = 0; reg < 4; reg++) {
                float f = acc[nt][reg] + bias;
                s += f > 0.f ? f : 0.f;
            }
            s += __shfl_xor(s, 16, 64);
            s += __shfl_xor(s, 32, 64);
            if (lane < 16) atomicAdd(&out[b0 * HID + nt * 16 + lane], s * rc);
        }
    } else {
#pragma unroll
        for (int nt = 0; nt < 8; nt++) {
            float bias = b2[nt * 16 + nloc];
            int cur = -1; float run = 0.f;
#pragma unroll
            for (int reg = 0; reg < 4; reg++) {
                int b = bch[w * 16 + quad * 4 + reg];
                if (b < 0) continue;
                float f = acc[nt][reg] + bias;
                f = f > 0.f ? f : 0.f;
                if (b != cur) {
                    if (cur >= 0) atomicAdd(&out[cur * HID + nt * 16 + nloc], run * rcnt[cur]);
                    run = 0.f; cur = b;
                }
                run += f;
            }
            if (cur >= 0) atomicAdd(&out[cur * HID + nt * 16 + nloc], run * rcnt[cur]);
        }
    }
}

extern "C" void kernel_launch(void* const* d_in, const int* in_sizes, int n_in,
                              void* d_out, int out_size, void* d_ws, size_t ws_size,
                              hipStream_t stream) {
    const float* x   = (const float*)d_in[0];
    const int* ei    = (const int*)d_in[1];   // [2, E] flat: src then dst
    const int* batch = (const int*)d_in[2];
    const float* W1  = (const float*)d_in[3];
    const float* b1  = (const float*)d_in[4];
    const float* W2  = (const float*)d_in[5];
    const float* b2  = (const float*)d_in[6];
    float* out = (float*)d_out;

    int n  = in_sizes[0] / IN_C;
    int e  = in_sizes[1] / 2;
    int bg = out_size / HID;
    const int* src = ei;
    const int* dst = ei + e;

    size_t off_b = 0;
    char* base = (char*)d_ws;
    auto carve = [&](size_t bytes) -> void* {
        void* p = base + off_b;
        off_b += (bytes + 255) & ~(size_t)255;
        return p;
    };
    int*            cursor  = (int*)carve((size_t)n * 4);
    int*            slots   = (int*)carve((size_t)n * SLOT_C * 4);
    int*            ovf     = (int*)carve((size_t)OVF_CAP * 2 * 4);
    int*            ovf_cnt = (int*)carve(256);
    int*            pcur    = (int*)carve((size_t)NB * 4);
    unsigned*       elist   = (unsigned*)carve((size_t)NB * ECAP * 4);  // packed 4B
    float*          dinv    = (float*)carve((size_t)n * 4);
    unsigned*       f1p     = (unsigned*)carve((size_t)n * 64 * 4);    // bf16-packed
    unsigned*       acc2b   = (unsigned*)carve((size_t)n * 64 * 4);    // bf16-packed
    unsigned short* w2f     = (unsigned short*)carve((size_t)HID * HID * 2);
    float*          rcnt    = (float*)carve((size_t)bg * 4);
    (void)ws_size;

    int gN = (n + TPB - 1) / TPB;
    int gP = (e + 256 * EPT - 1) / (256 * EPT);

    k_prep<<<gN + 64 + 1, TPB, 0, stream>>>(out, n, out_size, W2, w2f,
                                            batch, rcnt, bg, ovf_cnt, pcur);
    k_part<<<gP, TPB, 0, stream>>>(src, dst, elist, pcur, e, n);
    k_build<<<NB, TPB, 0, stream>>>(elist, pcur, cursor, dinv, slots, ovf, ovf_cnt, n);
    k_g1f1<<<gN, TPB, 0, stream>>>(cursor, slots, ovf, ovf_cnt, dinv, x, W1, b1, f1p, n);
    k_gather2<<<(n + 1) / 2, 128, 0, stream>>>(cursor, slots, ovf, ovf_cnt, dinv, f1p, acc2b, n);
    k_mm2_pool<<<(n + 63) / 64, 256, 0, stream>>>(acc2b, w2f, b2, batch, rcnt, out, n);
}

// Round 8
// 242.088 us; speedup vs baseline: 1.1794x; 1.0012x over previous
//
#include <hip/hip_runtime.h>

#define TPB 256
#define HID 128
#define IN_C 4
#define SLOT_C 32          // per-node slot capacity; Poisson(16): P(deg>32)~1e-4,
                           // ~10 overflow nodes @ n=1e5 -> ovf list handles them.
#define NB 512             // dst-range buckets (~196 nodes each @ n=1e5)
#define EPT 8              // edges per thread in k_part
#define ECAP 4096          // per-bucket edge capacity (mean 3125, sigma 56 -> 17 sigma)
#define OVF_CAP 131072     // overflow pairs capacity (statistically needs ~100)

typedef __attribute__((ext_vector_type(8))) short bf16x8;   // 8 bf16 = 4 VGPRs
typedef __attribute__((ext_vector_type(4))) float f32x4;

union FragU { uint4 u; bf16x8 b; };

// bf16 helpers: pack with RNE, unpack with shift (values finite, no NaN)
__device__ __forceinline__ unsigned f2bf(float f) {
    unsigned u = __float_as_uint(f);
    return (u + 0x7fffu + ((u >> 16) & 1u)) >> 16;
}
__device__ __forceinline__ float bf_lo(unsigned u) { return __uint_as_float(u << 16); }
__device__ __forceinline__ float bf_hi(unsigned u) { return __uint_as_float(u & 0xffff0000u); }

// ---------------------------------------------------------------------------
// K0: fused prep — role by blockIdx: [0,nbA) zero out (cursor zeroing dropped:
// k_build fully rewrites cursor); [nbA,nbA+64) w2frag swizzle; last block:
// per-graph 1/cnt + ovf_cnt=0 + pcur[NB]=0.
__global__ void k_prep(float* out, int n, int outsz,
                       const float* __restrict__ W2, unsigned short* w2f,
                       const int* __restrict__ batch, float* rcnt, int bg,
                       int* ovf_cnt, int* pcur) {
    int nbA = (n + TPB - 1) / TPB;
    int b = blockIdx.x;
    if (b < nbA) {
        int i = b * TPB + threadIdx.x;
        if (i < outsz) out[i] = 0.0f;
    } else if (b < nbA + 64) {
        int i = (b - nbA) * TPB + threadIdx.x;   // 0..16383
        if (i < HID * HID) {
            int j = i & 7, frag = i >> 3;
            int lane = frag & 63, blk = frag >> 6;       // blk = kk*8 + nt
            int kk = blk >> 3, nt = blk & 7;
            int quad = lane >> 4, nloc = lane & 15;
            int k = kk * 32 + quad * 8 + j;
            int c = nt * 16 + nloc;
            w2f[i] = (unsigned short)f2bf(W2[k * HID + c]);
        }
    } else {
        int g = threadIdx.x;
        if (g == 0) *ovf_cnt = 0;
        for (int z = g; z < NB; z += TPB) pcur[z] = 0;
        if (g < bg) {
            int lo0 = 0, hi0 = n;
            while (lo0 < hi0) { int m = (lo0 + hi0) >> 1; if (batch[m] < g) lo0 = m + 1; else hi0 = m; }
            int lo1 = lo0, hi1 = n;
            while (lo1 < hi1) { int m = (lo1 + hi1) >> 1; if (batch[m] < g + 1) lo1 = m + 1; else hi1 = m; }
            int c = lo1 - lo0;
            rcnt[g] = 1.0f / (float)(c > 1 ? c : 1);
        }
    }
}

// K1a: bucket edges into NB=512 dst-range buckets, one pass. Rank via
// 2-copy x 512-counter LDS histogram (half-wave picks its copy).
// elist entry is PACKED 4B: s | ((d - nlo(p)) << 17).
__global__ __launch_bounds__(256) void k_part(
        const int* __restrict__ src, const int* __restrict__ dst,
        unsigned* elist, int* pcur, int e, int n) {
    __shared__ int lcnt[2][NB];
    __shared__ int lbase[NB];
    int t = threadIdx.x;
    int c = (t >> 5) & 1;                    // half-wave copy id
    for (int z = t; z < NB; z += 256) { lcnt[0][z] = 0; lcnt[1][z] = 0; }
    __syncthreads();

    int base_i = blockIdx.x * (256 * EPT);
    unsigned u[EPT]; int pr[EPT];
#pragma unroll
    for (int k = 0; k < EPT; k++) {
        int i = base_i + k * 256 + t;
        if (i < e) {
            int s = src[i];
            int d = dst[i];
            int p = (int)(((long long)d * NB) / n);
            int nlo = (int)(((long long)p * n + NB - 1) / NB);   // ceil(p*n/NB)
            int r = atomicAdd(&lcnt[c][p], 1);     // LDS, ~conflict-free
            pr[k] = p | (r << 9);                   // p<512, r<2048
            u[k] = (unsigned)s | ((unsigned)(d - nlo) << 17);
        } else {
            pr[k] = -1;
        }
    }
    __syncthreads();

    for (int z = t; z < NB; z += 256) {
        int tot = lcnt[0][z] + lcnt[1][z];
        lbase[z] = tot ? atomicAdd(&pcur[z], tot) : 0;
    }
    __syncthreads();

#pragma unroll
    for (int k = 0; k < EPT; k++) {
        if (pr[k] >= 0) {
            int p = pr[k] & (NB - 1);
            int r = pr[k] >> 9;
            int idx = lbase[p] + (c ? lcnt[0][p] : 0) + r;
            if (idx < ECAP)                         // 17-sigma slack; never taken
                elist[(size_t)p * ECAP + idx] = u[k];
        }
    }
}

// K1b: build slots, ONE BLOCK PER BUCKET. Per-node cursors in LDS; zero
// global atomics on the hot path; degrees + dinv written once per node at
// the end (k_dinv folded in here). Reads packed 4B elist entries.
__global__ __launch_bounds__(256) void k_build(
        const unsigned* __restrict__ elist, const int* __restrict__ pcur,
        int* cursor, float* dinv, int* slots, int* ovf, int* ovf_cnt, int n) {
    __shared__ int lcur[512];                // covers n <= NB*512
    int p = blockIdx.x;
    int t = threadIdx.x;
    int nlo = (int)(((long long)p * n + NB - 1) / NB);       // ceil(p*n/NB)
    int nhi = (int)(((long long)(p + 1) * n + NB - 1) / NB);
    int nn = nhi - nlo;
    for (int z = t; z < nn; z += 256) lcur[z] = 0;
    __syncthreads();

    int ne = pcur[p];
    if (ne > ECAP) ne = ECAP;
    for (int j = t; j < ne; j += 256) {
        unsigned u = elist[(size_t)p * ECAP + j];
        int s = (int)(u & 0x1FFFFu);
        int dloc = (int)(u >> 17);
        int pos = atomicAdd(&lcur[dloc], 1);
        if (pos < SLOT_C) {
            slots[(nlo + dloc) * SLOT_C + pos] = s;
        } else {                              // rare (P~1e-4 per node)
            int o = atomicAdd(ovf_cnt, 1);
            if (o < OVF_CAP) {
                ovf[2 * o] = s;
                ovf[2 * o + 1] = nlo + dloc;
            }
        }
    }
    __syncthreads();
    for (int z = t; z < nn; z += 256) {
        int dg = lcur[z];
        cursor[nlo + z] = dg;
        dinv[nlo + z] = rsqrtf((float)dg + 1.0f);
    }
}

// K6: FUSED layer-1 gather + W1 MLP -> packed bf16 f1p (row-major: 64 words
// = 128 channels per node).
__global__ __launch_bounds__(256) void k_g1f1(
        const int* __restrict__ cursor, const int* __restrict__ slots,
        const int* __restrict__ ovf, const int* __restrict__ ovf_cnt,
        const float* __restrict__ dinv, const float* __restrict__ x,
        const float* __restrict__ W1, const float* __restrict__ b1,
        unsigned* f1p, int n) {
    __shared__ float xs[256 * 5];
    int t = threadIdx.x;
    int v0 = blockIdx.x * 256;

    // ---- phase A: gather (one thread per node) ----
    int v = v0 + t;
    if (v < n) {
        float dv = dinv[v];
        const float4* x4 = (const float4*)x;
        float4 xv = x4[v];
        float sl = dv * dv;
        float4 A = make_float4(sl * xv.x, sl * xv.y, sl * xv.z, sl * xv.w);
        float4 B = make_float4(0.f, 0.f, 0.f, 0.f);
        float4 C = make_float4(0.f, 0.f, 0.f, 0.f);
        float4 D = make_float4(0.f, 0.f, 0.f, 0.f);
        int deg = cursor[v];
        int m = deg < SLOT_C ? deg : SLOT_C;
        const int* sb = slots + v * SLOT_C;
        int e = 0;
        for (; e + 4 <= m; e += 4) {
            int s0 = sb[e], s1 = sb[e + 1], s2 = sb[e + 2], s3 = sb[e + 3];
            float n0 = dinv[s0] * dv, n1 = dinv[s1] * dv;
            float n2 = dinv[s2] * dv, n3 = dinv[s3] * dv;
            float4 r0 = x4[s0], r1 = x4[s1], r2 = x4[s2], r3 = x4[s3];
            A.x = fmaf(n0, r0.x, A.x); A.y = fmaf(n0, r0.y, A.y);
            A.z = fmaf(n0, r0.z, A.z); A.w = fmaf(n0, r0.w, A.w);
            B.x = fmaf(n1, r1.x, B.x); B.y = fmaf(n1, r1.y, B.y);
            B.z = fmaf(n1, r1.z, B.z); B.w = fmaf(n1, r1.w, B.w);
            C.x = fmaf(n2, r2.x, C.x); C.y = fmaf(n2, r2.y, C.y);
            C.z = fmaf(n2, r2.z, C.z); C.w = fmaf(n2, r2.w, C.w);
            D.x = fmaf(n3, r3.x, D.x); D.y = fmaf(n3, r3.y, D.y);
            D.z = fmaf(n3, r3.z, D.z); D.w = fmaf(n3, r3.w, D.w);
        }
        for (; e < m; e++) {
            int s = sb[e];
            float nm = dinv[s] * dv;
            float4 r = x4[s];
            A.x = fmaf(nm, r.x, A.x); A.y = fmaf(nm, r.y, A.y);
            A.z = fmaf(nm, r.z, A.z); A.w = fmaf(nm, r.w, A.w);
        }
        if (deg > SLOT_C) {              // only truncated nodes scan the list
            int oc = *ovf_cnt;
            for (int k = 0; k < oc; k++) {
                if (ovf[2 * k + 1] == v) {
                    int s = ovf[2 * k];
                    float nm = dinv[s] * dv;
                    float4 r = x4[s];
                    A.x = fmaf(nm, r.x, A.x); A.y = fmaf(nm, r.y, A.y);
                    A.z = fmaf(nm, r.z, A.z); A.w = fmaf(nm, r.w, A.w);
                }
            }
        }
        xs[t * 5 + 0] = (A.x + B.x) + (C.x + D.x);
        xs[t * 5 + 1] = (A.y + B.y) + (C.y + D.y);
        xs[t * 5 + 2] = (A.z + B.z) + (C.z + D.z);
        xs[t * 5 + 3] = (A.w + B.w) + (C.w + D.w);
    }
    __syncthreads();

    // ---- phase B: W1 MLP + relu + bf16 pack ----
    int cp = t & 63;                     // constant per thread
    int c0 = cp * 2, c1 = c0 + 1;
    float w00 = W1[c0],           w01 = W1[c1];
    float w10 = W1[HID + c0],     w11 = W1[HID + c1];
    float w20 = W1[2 * HID + c0], w21 = W1[2 * HID + c1];
    float w30 = W1[3 * HID + c0], w31 = W1[3 * HID + c1];
    float bb0 = b1[c0],           bb1 = b1[c1];
    int g = t >> 6;                      // node sub-group 0..3 (wave-uniform)
    for (int iter = 0; iter < 64; iter++) {
        int node = iter * 4 + g;
        int vv = v0 + node;
        if (vv >= n) break;              // wave-uniform
        float x0 = xs[node * 5 + 0], x1 = xs[node * 5 + 1];
        float x2 = xs[node * 5 + 2], x3 = xs[node * 5 + 3];
        float s0 = fmaf(x0, w00, fmaf(x1, w10, fmaf(x2, w20, fmaf(x3, w30, bb0))));
        float s1 = fmaf(x0, w01, fmaf(x1, w11, fmaf(x2, w21, fmaf(x3, w31, bb1))));
        s0 = s0 > 0.0f ? s0 : 0.0f;
        s1 = s1 > 0.0f ? s1 : 0.0f;
        f1p[(size_t)vv * 64 + cp] = f2bf(s0) | (f2bf(s1) << 16);
    }
}

// K8+K9 MERGED, wave-parallel: block = 1024 thr = 16 waves = 16 nodes = one
// M=16 MFMA tile. Each wave runs the round-2 gather body for ITS node (1
// node/wave preserved -> TLP intact, unlike the round-6 serial-16 failure),
// writes its 256B row to LDS; one barrier; waves 0..7 each take one nt
// column (acc = 1 f32x4) and do the 4-MFMA + bias/ReLU/mean-pool epilogue.
// Kills the 25MB acc2b write + 25.6MB re-read + 1 launch.
__global__ __launch_bounds__(1024, 8) void k_g2mm(
        const int* __restrict__ cursor, const int* __restrict__ slots,
        const int* __restrict__ ovf, const int* __restrict__ ovf_cnt,
        const float* __restrict__ dinv, const unsigned* __restrict__ f1p,
        const unsigned short* __restrict__ w2f, const float* __restrict__ b2,
        const int* __restrict__ batch, const float* __restrict__ rcnt,
        float* out, int n) {
    __shared__ unsigned arow[16][68];
    __shared__ int bch[16];
    int t = threadIdx.x;
    int w = t >> 6, ln = t & 63;
    int v0 = blockIdx.x * 16;
    if (t < 16) bch[t] = (v0 + t < n) ? batch[v0 + t] : -1;

    // ---- phase 1: gather, one node per wave (round-2 body) ----
    int h = ln >> 5;                     // half = edge parity
    int q = ln & 31;                     // channel quad: ch 4q..4q+3
    int v = v0 + w;
    const uint2* F = (const uint2*)f1p;  // row = 32 uint2
    if (v < n) {
        float dv = dinv[v];
        uint2 us = F[(size_t)v * 32 + q];
        float sl = (h == 0) ? dv * dv : 0.0f;
        float A[4] = { sl * bf_lo(us.x), sl * bf_hi(us.x),
                       sl * bf_lo(us.y), sl * bf_hi(us.y) };
        float B[4] = {0.f, 0.f, 0.f, 0.f};
        float C[4] = {0.f, 0.f, 0.f, 0.f};
        float D[4] = {0.f, 0.f, 0.f, 0.f};

        int deg = cursor[v];
        int m = deg < SLOT_C ? deg : SLOT_C;
        const int* sb = slots + v * SLOT_C;
        int e = 0;
        for (; e + 8 <= m; e += 8) {
            int sA = sb[e + h];
            int sB = sb[e + 2 + h];
            int sC = sb[e + 4 + h];
            int sD = sb[e + 6 + h];
            float nA = dinv[sA] * dv, nB = dinv[sB] * dv;
            float nC = dinv[sC] * dv, nD = dinv[sD] * dv;
            uint2 uA = F[(size_t)sA * 32 + q];
            uint2 uB = F[(size_t)sB * 32 + q];
            uint2 uC = F[(size_t)sC * 32 + q];
            uint2 uD = F[(size_t)sD * 32 + q];
            A[0] = fmaf(nA, bf_lo(uA.x), A[0]); A[1] = fmaf(nA, bf_hi(uA.x), A[1]);
            A[2] = fmaf(nA, bf_lo(uA.y), A[2]); A[3] = fmaf(nA, bf_hi(uA.y), A[3]);
            B[0] = fmaf(nB, bf_lo(uB.x), B[0]); B[1] = fmaf(nB, bf_hi(uB.x), B[1]);
            B[2] = fmaf(nB, bf_lo(uB.y), B[2]); B[3] = fmaf(nB, bf_hi(uB.y), B[3]);
            C[0] = fmaf(nC, bf_lo(uC.x), C[0]); C[1] = fmaf(nC, bf_hi(uC.x), C[1]);
            C[2] = fmaf(nC, bf_lo(uC.y), C[2]); C[3] = fmaf(nC, bf_hi(uC.y), C[3]);
            D[0] = fmaf(nD, bf_lo(uD.x), D[0]); D[1] = fmaf(nD, bf_hi(uD.x), D[1]);
            D[2] = fmaf(nD, bf_lo(uD.y), D[2]); D[3] = fmaf(nD, bf_hi(uD.y), D[3]);
        }
        for (; e + 2 <= m; e += 2) {
            int s = sb[e + h];
            float nm = dinv[s] * dv;
            uint2 u = F[(size_t)s * 32 + q];
            A[0] = fmaf(nm, bf_lo(u.x), A[0]); A[1] = fmaf(nm, bf_hi(u.x), A[1]);
            A[2] = fmaf(nm, bf_lo(u.y), A[2]); A[3] = fmaf(nm, bf_hi(u.y), A[3]);
        }
        if (e < m) {                     // odd tail: half 0 only
            int s = sb[e];
            float nm = (h == 0) ? dinv[s] * dv : 0.0f;
            uint2 u = F[(size_t)s * 32 + q];
            A[0] = fmaf(nm, bf_lo(u.x), A[0]); A[1] = fmaf(nm, bf_hi(u.x), A[1]);
            A[2] = fmaf(nm, bf_lo(u.y), A[2]); A[3] = fmaf(nm, bf_hi(u.y), A[3]);
        }
        if (deg > SLOT_C) {              // only truncated nodes scan the list
            int oc = *ovf_cnt;
            for (int k = 0; k < oc; k++) {
                if (ovf[2 * k + 1] == v && h == 0) {
                    int s = ovf[2 * k];
                    float nm = dinv[s] * dv;
                    uint2 u = F[(size_t)s * 32 + q];
                    A[0] = fmaf(nm, bf_lo(u.x), A[0]); A[1] = fmaf(nm, bf_hi(u.x), A[1]);
                    A[2] = fmaf(nm, bf_lo(u.y), A[2]); A[3] = fmaf(nm, bf_hi(u.y), A[3]);
                }
            }
        }

        float o0 = (A[0] + B[0]) + (C[0] + D[0]);
        float o1 = (A[1] + B[1]) + (C[1] + D[1]);
        float o2 = (A[2] + B[2]) + (C[2] + D[2]);
        float o3 = (A[3] + B[3]) + (C[3] + D[3]);
        o0 += __shfl_xor(o0, 32, 64);
        o1 += __shfl_xor(o1, 32, 64);
        o2 += __shfl_xor(o2, 32, 64);
        o3 += __shfl_xor(o3, 32, 64);
        if (h == 0) {
            arow[w][2 * q]     = f2bf(o0) | (f2bf(o1) << 16);
            arow[w][2 * q + 1] = f2bf(o2) | (f2bf(o3) << 16);
        }
    } else {
        if (h == 0) { arow[w][2 * q] = 0; arow[w][2 * q + 1] = 0; }
    }
    __syncthreads();

    // ---- phase 2: MFMA + bias/ReLU/mean-pool, one nt column per wave ----
    if (w < 8) {
        int nt = w;
        int lane = ln;
        int quad = lane >> 4, nloc = lane & 15;
        const uint4* B4 = (const uint4*)w2f;        // frag blk = 64 uint4

        f32x4 acc = (f32x4){0.f, 0.f, 0.f, 0.f};
#pragma unroll
        for (int kk = 0; kk < 4; kk++) {
            FragU af, bf;
            af.u = *(const uint4*)&arow[nloc][(kk * 4 + quad) * 4];
            bf.u = B4[(kk * 8 + nt) * 64 + lane];
            acc = __builtin_amdgcn_mfma_f32_16x16x32_bf16(af.b, bf.b, acc, 0, 0, 0);
        }

        int b0 = bch[0], b15 = bch[15];
        float bias = b2[nt * 16 + nloc];
        if (b0 == b15 && b0 >= 0) {
            float rc = rcnt[b0];
            float s = 0.f;
#pragma unroll
            for (int reg = 0; reg < 4; reg++) {
                float f = acc[reg] + bias;
                s += f > 0.f ? f : 0.f;
            }
            s += __shfl_xor(s, 16, 64);
            s += __shfl_xor(s, 32, 64);
            if (lane < 16) atomicAdd(&out[b0 * HID + nt * 16 + lane], s * rc);
        } else {
            int cur = -1; float run = 0.f;
#pragma unroll
            for (int reg = 0; reg < 4; reg++) {
                int b = bch[quad * 4 + reg];
                if (b < 0) continue;
                float f = acc[reg] + bias;
                f = f > 0.f ? f : 0.f;
                if (b != cur) {
                    if (cur >= 0) atomicAdd(&out[cur * HID + nt * 16 + nloc], run * rcnt[cur]);
                    run = 0.f; cur = b;
                }
                run += f;
            }
            if (cur >= 0) atomicAdd(&out[cur * HID + nt * 16 + nloc], run * rcnt[cur]);
        }
    }
}

extern "C" void kernel_launch(void* const* d_in, const int* in_sizes, int n_in,
                              void* d_out, int out_size, void* d_ws, size_t ws_size,
                              hipStream_t stream) {
    const float* x   = (const float*)d_in[0];
    const int* ei    = (const int*)d_in[1];   // [2, E] flat: src then dst
    const int* batch = (const int*)d_in[2];
    const float* W1  = (const float*)d_in[3];
    const float* b1  = (const float*)d_in[4];
    const float* W2  = (const float*)d_in[5];
    const float* b2  = (const float*)d_in[6];
    float* out = (float*)d_out;

    int n  = in_sizes[0] / IN_C;
    int e  = in_sizes[1] / 2;
    int bg = out_size / HID;
    const int* src = ei;
    const int* dst = ei + e;

    size_t off_b = 0;
    char* base = (char*)d_ws;
    auto carve = [&](size_t bytes) -> void* {
        void* p = base + off_b;
        off_b += (bytes + 255) & ~(size_t)255;
        return p;
    };
    int*            cursor  = (int*)carve((size_t)n * 4);
    int*            slots   = (int*)carve((size_t)n * SLOT_C * 4);
    int*            ovf     = (int*)carve((size_t)OVF_CAP * 2 * 4);
    int*            ovf_cnt = (int*)carve(256);
    int*            pcur    = (int*)carve((size_t)NB * 4);
    unsigned*       elist   = (unsigned*)carve((size_t)NB * ECAP * 4);  // packed 4B
    float*          dinv    = (float*)carve((size_t)n * 4);
    unsigned*       f1p     = (unsigned*)carve((size_t)n * 64 * 4);    // bf16-packed
    unsigned short* w2f     = (unsigned short*)carve((size_t)HID * HID * 2);
    float*          rcnt    = (float*)carve((size_t)bg * 4);
    (void)ws_size;

    int gN = (n + TPB - 1) / TPB;
    int gP = (e + 256 * EPT - 1) / (256 * EPT);

    k_prep<<<gN + 64 + 1, TPB, 0, stream>>>(out, n, out_size, W2, w2f,
                                            batch, rcnt, bg, ovf_cnt, pcur);
    k_part<<<gP, TPB, 0, stream>>>(src, dst, elist, pcur, e, n);
    k_build<<<NB, TPB, 0, stream>>>(elist, pcur, cursor, dinv, slots, ovf, ovf_cnt, n);
    k_g1f1<<<gN, TPB, 0, stream>>>(cursor, slots, ovf, ovf_cnt, dinv, x, W1, b1, f1p, n);
    k_g2mm<<<(n + 15) / 16, 1024, 0, stream>>>(cursor, slots, ovf, ovf_cnt, dinv, f1p,
                                               w2f, b2, batch, rcnt, out, n);
}